// Round 17
// baseline (311.553 us; speedup 1.0000x reference)
//
#include <hip/hip_runtime.h>
#include <hip/hip_bf16.h>
#include <math.h>

typedef __attribute__((ext_vector_type(8))) short short8;
typedef __attribute__((ext_vector_type(4))) float f32x4;
typedef __attribute__((ext_vector_type(4))) int i32x4;

__device__ inline ushort f2bf(float f) {
    uint u = __builtin_bit_cast(uint, f);
    u += 0x7fffu + ((u >> 16) & 1u);          // round-to-nearest-even
    return (ushort)(u >> 16);
}
__device__ inline float bf2f(ushort h) {
    return __builtin_bit_cast(float, (uint)h << 16);
}

// ================= CSR build: fixed-capacity bucket counting-sort =================

#define NB   256
#define BKE  2048
#define CAP  16384
#define MAXBE 16384

__device__ inline int bucket_of(int d, int W, float recipW) {
    int g = (int)((float)d * recipW);
    if (g > NB - 1) g = NB - 1;
    if (g < 0) g = 0;
    while (d < g * W) --g;
    while (d >= (g + 1) * W) ++g;
    return g;
}

__global__ __launch_bounds__(256) void bucket_kernel(const int* __restrict__ src, const int* __restrict__ dst,
                                                     int* __restrict__ cursor256, int* __restrict__ epk,
                                                     int E, int W, float recipW) {
    __shared__ int hist[NB];
    __shared__ int base[NB];
    int tid = threadIdx.x;
    int e0 = blockIdx.x * BKE;
    if (e0 >= E) return;
    int e1 = e0 + BKE; if (e1 > E) e1 = E;
    int n4 = (e1 - e0) >> 2;                  // int4 count
    hist[tid] = 0;
    __syncthreads();
    const i32x4* d4 = (const i32x4*)(dst + e0);
    const i32x4* s4 = (const i32x4*)(src + e0);
    int myp[8], myg[8], myr[8];
    #pragma unroll
    for (int i = 0; i < 2; ++i) {
        int q = i * 256 + tid;
        if (q < n4) {
            i32x4 dv = d4[q];
            i32x4 sv = s4[q];
            #pragma unroll
            for (int j = 0; j < 4; ++j) {
                int d = dv[j];
                int g = bucket_of(d, W, recipW);
                myp[i * 4 + j] = sv[j] | ((d - g * W) << 17);
                myg[i * 4 + j] = g;
                myr[i * 4 + j] = atomicAdd(&hist[g], 1);
            }
        } else {
            #pragma unroll
            for (int j = 0; j < 4; ++j) myg[i * 4 + j] = -1;
        }
    }
    // scalar tail (E % 4 != 0 safety; empty for this shape)
    int tg = -1, tp = 0, tr = 0;
    for (int e = e0 + n4 * 4 + tid; e < e1; e += 256) {
        int d = dst[e];
        int g = bucket_of(d, W, recipW);
        tp = src[e] | ((d - g * W) << 17);
        tg = g;
        tr = atomicAdd(&hist[g], 1);
    }
    __syncthreads();
    base[tid] = atomicAdd(&cursor256[tid], hist[tid]);
    __syncthreads();
    #pragma unroll
    for (int i = 0; i < 8; ++i)
        if (myg[i] >= 0)
            epk[base[myg[i]] + myr[i]] = myp[i];
    if (tg >= 0) epk[base[tg] + tr] = tp;
}

// one block per bucket: inline 256-scan of cursors -> hist -> scan -> offs/dinv -> scatter -> csr
__global__ __launch_bounds__(256) void sortcsr_kernel(const int* __restrict__ epk,
                                                      const int* __restrict__ cursor256,
                                                      int* __restrict__ csr, int* __restrict__ offs,
                                                      float* __restrict__ dinv, int N, int W, int E) {
    __shared__ int lcnt[512];
    __shared__ int lofs[513];
    __shared__ int tmp[256];
    __shared__ int lcsr[MAXBE];
    int b = blockIdx.x;
    int lo = b * W;
    int nloc = N - lo; if (nloc > W) nloc = W; if (nloc < 0) nloc = 0;
    int ebk = b * CAP;
    int tid = threadIdx.x;
    lcnt[2 * tid] = 0; lcnt[2 * tid + 1] = 0;
    tmp[tid] = cursor256[tid] - tid * CAP;    // per-bucket count
    __syncthreads();
    for (int off = 1; off < 256; off <<= 1) {
        int t = (tid >= off) ? tmp[tid - off] : 0;
        __syncthreads();
        tmp[tid] += t;
        __syncthreads();
    }
    int incl = tmp[b];
    int cnt = (b == 0) ? incl : incl - tmp[b - 1];
    int gbase = incl - cnt;
    __syncthreads();                          // all reads of tmp done before reuse
    for (int e = tid; e < cnt; e += 256)
        atomicAdd(&lcnt[epk[ebk + e] >> 17], 1);
    __syncthreads();
    int a0 = lcnt[2 * tid], a1 = lcnt[2 * tid + 1];
    int psum = a0 + a1;
    tmp[tid] = psum;
    __syncthreads();
    for (int off = 1; off < 256; off <<= 1) {
        int t = (tid >= off) ? tmp[tid - off] : 0;
        __syncthreads();
        tmp[tid] += t;
        __syncthreads();
    }
    int excl = tmp[tid] - psum;
    lofs[2 * tid] = excl;
    lofs[2 * tid + 1] = excl + a0;
    lcnt[2 * tid] = excl;
    lcnt[2 * tid + 1] = excl + a0;
    if (tid == 255) lofs[512] = tmp[255];
    __syncthreads();
    for (int t = tid; t < nloc; t += 256) {
        offs[lo + t] = gbase + lofs[t];
        int deg = lofs[t + 1] - lofs[t];
        dinv[lo + t] = rsqrtf((float)(deg + 1));
    }
    if (b == NB - 1 && tid == 0) offs[N] = E;
    for (int e = tid; e < cnt; e += 256) {
        int p = epk[ebk + e];
        int pos = atomicAdd(&lcnt[p >> 17], 1);
        int sv = p & 0x1FFFF;
        if (pos < MAXBE) lcsr[pos] = sv;
        else csr[gbase + pos] = sv;
    }
    __syncthreads();
    int ne = cnt; if (ne > MAXBE) ne = MAXBE;
    for (int e = tid; e < ne; e += 256) csr[gbase + e] = lcsr[e];
}

// ---------------- weight prep (Wt pre-swizzled per 32-k group: chunk c holds c^(row&3)) ------
// + bucket-cursor init (block 0)

__global__ __launch_bounds__(256) void prep_kernel(const float* __restrict__ W1a, const float* __restrict__ W1b,
                                                   const float* __restrict__ W2a, const float* __restrict__ W2b,
                                                   const float* __restrict__ b1a, const float* __restrict__ b1b,
                                                   const float* __restrict__ b2a, const float* __restrict__ b2b,
                                                   const float* __restrict__ W3a, const float* __restrict__ W3b,
                                                   const float* __restrict__ b3a, const float* __restrict__ b3b,
                                                   ushort* __restrict__ Wt, float* __restrict__ bcat,
                                                   float* __restrict__ W3s, float* __restrict__ b3s,
                                                   int* __restrict__ cursor256) {
    int idx = blockIdx.x * 256 + threadIdx.x;
    if (blockIdx.x == 0) cursor256[threadIdx.x] = threadIdx.x * CAP;
    if (idx < 128 * 512) {
        int row = idx >> 9, kk = idx & 511;
        int cstore = (kk >> 3) & 3;
        int clog = cstore ^ (row & 3);
        int klog = (kk & ~31) | (clog << 3) | (kk & 7);
        const float* Wsrc = (row < 32) ? W1a : (row < 64) ? W1b : (row < 96) ? W2a : W2b;
        Wt[idx] = f2bf(Wsrc[klog * 32 + (row & 31)]);
    }
    if (idx < 1280) W3s[idx] = W3a[idx] + W3b[idx];
    if (idx < 128) {
        const float* b = (idx < 32) ? b1a : (idx < 64) ? b1b : (idx < 96) ? b2a : b2b;
        bcat[idx] = b[idx & 31];
    }
    if (idx < 40) b3s[idx] = b3a[idx] + b3b[idx];
}

// ---------------- MFMA GEMM: HWp[N][128] = bf16( (X@Wcat)[r][c] * dinv[r] ) ----------------
// BK=32, async global_load_lds, single-buffered, 16KB LDS -> 8 blocks/CU (32 waves/CU).
// A pos (row,c) holds logical chunk c^(row&7) (swizzle in global src addr);
// B pos (row,c) holds logical chunk c^(row&3) (swizzle baked into Wt).

#define GBM 64

__global__ __launch_bounds__(256) void gemm_mfma(const float* __restrict__ X,
                                                 const ushort* __restrict__ Wt,
                                                 const float* __restrict__ dinv,
                                                 ushort* __restrict__ HWp, int N) {
    __shared__ float  Af[64 * 32];     // 8KB
    __shared__ ushort Bl[128 * 32];    // 8KB
    const int tid = threadIdx.x;
    const int lane = tid & 63;
    const int wave = tid >> 6;
    const int rQ = lane & 15, g = lane >> 4;
    const int rowBase = blockIdx.x * GBM;

    const float* agsrc[2];
    #pragma unroll
    for (int i = 0; i < 2; ++i) {
        int q = (i * 4 + wave) * 64 + lane;
        int row = q >> 3, c = q & 7;
        int rowg = rowBase + row; if (rowg > N - 1) rowg = N - 1;
        agsrc[i] = X + (size_t)rowg * 512 + ((c ^ (row & 7)) << 2);
    }
    const ushort* bgsrc[2];
    #pragma unroll
    for (int i = 0; i < 2; ++i) {
        int q = (i * 4 + wave) * 64 + lane;
        int row = q >> 2, c = q & 3;
        bgsrc[i] = Wt + (size_t)row * 512 + (c << 3);
    }

    f32x4 acc[4][2] = {};

#define STAGE(s)                                                              \
    {                                                                         \
        _Pragma("unroll")                                                     \
        for (int i = 0; i < 2; ++i)                                           \
            __builtin_amdgcn_global_load_lds(                                 \
                (const uint*)(agsrc[i] + (s) * 32),                           \
                (uint*)&Af[(i * 4 + wave) * 256], 16, 0, 0);                  \
        _Pragma("unroll")                                                     \
        for (int i = 0; i < 2; ++i)                                           \
            __builtin_amdgcn_global_load_lds(                                 \
                (const uint*)(bgsrc[i] + (s) * 32),                           \
                (uint*)&Bl[(i * 4 + wave) * 512], 16, 0, 0);                  \
    }

#define COMPUTE()                                                             \
    {                                                                         \
        short8 bfr[2];                                                        \
        _Pragma("unroll")                                                     \
        for (int ct2 = 0; ct2 < 2; ++ct2) {                                   \
            int brow = wave * 32 + ct2 * 16 + rQ;                             \
            bfr[ct2] = *(const short8*)(&Bl[brow * 32 + ((g ^ (brow & 3)) << 3)]); \
        }                                                                     \
        _Pragma("unroll")                                                     \
        for (int rt = 0; rt < 4; ++rt) {                                      \
            int arw = rt * 16 + rQ;                                           \
            float4 lo = *(const float4*)(&Af[arw * 32 + (((2 * g) ^ (arw & 7)) << 2)]);     \
            float4 hi = *(const float4*)(&Af[arw * 32 + (((2 * g + 1) ^ (arw & 7)) << 2)]); \
            union { short8 s8; __hip_bfloat162 h[4]; } u;                     \
            u.h[0] = __float22bfloat162_rn({lo.x, lo.y});                     \
            u.h[1] = __float22bfloat162_rn({lo.z, lo.w});                     \
            u.h[2] = __float22bfloat162_rn({hi.x, hi.y});                     \
            u.h[3] = __float22bfloat162_rn({hi.z, hi.w});                     \
            _Pragma("unroll")                                                 \
            for (int ct2 = 0; ct2 < 2; ++ct2)                                 \
                acc[rt][ct2] = __builtin_amdgcn_mfma_f32_16x16x32_bf16(       \
                    u.s8, bfr[ct2], acc[rt][ct2], 0, 0, 0);                   \
        }                                                                     \
    }

    for (int s = 0; s < 16; ++s) {
        STAGE(s);
        __syncthreads();
        COMPUTE();
        __syncthreads();
    }

    #pragma unroll
    for (int rt = 0; rt < 4; ++rt) {
        #pragma unroll
        for (int j = 0; j < 4; ++j) {
            int r = rowBase + rt * 16 + g * 4 + j;
            if (r < N) {
                float dv = dinv[r];
                #pragma unroll
                for (int ct2 = 0; ct2 < 2; ++ct2) {
                    int c = wave * 32 + ct2 * 16 + rQ;
                    HWp[(size_t)r * 128 + c] = f2bf(acc[rt][ct2][j] * dv);
                }
            }
        }
    }
#undef STAGE
#undef COMPUTE
}

// ---------------- aggregation 128: 16 lanes/node x 16B, unroll 8 ----------------

__global__ __launch_bounds__(256) void agg128(const ushort* __restrict__ HWp, const float* __restrict__ dinv,
                                              const int* __restrict__ offs, const int* __restrict__ csr,
                                              const float* __restrict__ bcat, ushort* __restrict__ xsp, int N) {
    int t = blockIdx.x * 256 + threadIdx.x;
    int node = t >> 4, c = t & 15;
    if (node >= N) return;
    const short8* H = (const short8*)HWp;
    short8 h = H[(size_t)node * 16 + c];
    float a[8];
    #pragma unroll
    for (int i = 0; i < 8; ++i) a[i] = bf2f((ushort)h[i]);
    int j = offs[node];
    int e1 = offs[node + 1];
    int jend = j + ((e1 - j) & ~7);
    for (; j < jend; j += 8) {
        int s[8];
        #pragma unroll
        for (int q = 0; q < 8; ++q) s[q] = csr[j + q];
        short8 v[8];
        #pragma unroll
        for (int q = 0; q < 8; ++q) v[q] = H[(size_t)s[q] * 16 + c];
        #pragma unroll
        for (int q = 0; q < 8; ++q)
            #pragma unroll
            for (int i = 0; i < 8; ++i) a[i] += bf2f((ushort)v[q][i]);
    }
    for (; j < e1; ++j) {
        short8 v = H[(size_t)csr[j] * 16 + c];
        #pragma unroll
        for (int i = 0; i < 8; ++i) a[i] += bf2f((ushort)v[i]);
    }
    float di = dinv[node];
    float4 b0 = *(const float4*)(bcat + c * 8);
    float4 b1 = *(const float4*)(bcat + c * 8 + 4);
    float bb[8] = {b0.x, b0.y, b0.z, b0.w, b1.x, b1.y, b1.z, b1.w};
    float r[8];
    #pragma unroll
    for (int i = 0; i < 8; ++i) r[i] = fmaxf(di * a[i] + bb[i], 0.f);
    #pragma unroll
    for (int i = 0; i < 8; ++i) { r[i] += __shfl_xor(r[i], 4); r[i] += __shfl_xor(r[i], 8); }
    if ((c & 12) == 0) {
        union { short8 s8; ushort us[8]; } o;
        #pragma unroll
        for (int i = 0; i < 8; ++i) o.us[i] = f2bf(r[i] * di);
        *(short8*)(xsp + (size_t)node * 32 + c * 8) = o.s8;
    }
}

// ---------------- aggregation 32 FUSED with final matvec + log_softmax ----------------

__global__ __launch_bounds__(256) void agg32f(const ushort* __restrict__ xsp, const float* __restrict__ dinv,
                                              const int* __restrict__ offs, const int* __restrict__ csr,
                                              const float* __restrict__ W3s, const float* __restrict__ b3s,
                                              float* __restrict__ out, int N) {
    __shared__ float w[32 * 40];
    __shared__ float bsh[40];
    int tid = threadIdx.x;
    for (int i = tid; i < 1280; i += 256) w[i] = W3s[i];
    if (tid < 40) bsh[tid] = b3s[tid];
    __syncthreads();

    int t = blockIdx.x * 256 + tid;
    int node = t >> 2, l = t & 3;
    if (node >= N) return;
    const short8* Xr = (const short8*)xsp;
    short8 h = Xr[(size_t)node * 4 + l];
    float a[8];
    #pragma unroll
    for (int i = 0; i < 8; ++i) a[i] = bf2f((ushort)h[i]);
    int j = offs[node];
    int e1 = offs[node + 1];
    int jend = j + ((e1 - j) & ~7);
    for (; j < jend; j += 8) {
        int s[8];
        #pragma unroll
        for (int q = 0; q < 8; ++q) s[q] = csr[j + q];
        short8 v[8];
        #pragma unroll
        for (int q = 0; q < 8; ++q) v[q] = Xr[(size_t)s[q] * 4 + l];
        #pragma unroll
        for (int q = 0; q < 8; ++q)
            #pragma unroll
            for (int i = 0; i < 8; ++i) a[i] += bf2f((ushort)v[q][i]);
    }
    for (; j < e1; ++j) {
        short8 v = Xr[(size_t)csr[j] * 4 + l];
        #pragma unroll
        for (int i = 0; i < 8; ++i) a[i] += bf2f((ushort)v[i]);
    }
    float di = dinv[node];

    float lg[40];
    #pragma unroll
    for (int c = 0; c < 40; ++c) lg[c] = 0.f;
    #pragma unroll
    for (int k = 0; k < 8; ++k) {
        float av = a[k] * di;
        const float* wr = &w[(l * 8 + k) * 40];
        #pragma unroll
        for (int c = 0; c < 40; ++c) lg[c] += av * wr[c];
    }
    #pragma unroll
    for (int c = 0; c < 40; ++c) {
        lg[c] += __shfl_xor(lg[c], 1);
        lg[c] += __shfl_xor(lg[c], 2);
        lg[c] += bsh[c];
    }
    float m = lg[0];
    #pragma unroll
    for (int c = 1; c < 40; ++c) m = fmaxf(m, lg[c]);
    float sum = 0.f;
    #pragma unroll
    for (int c = 0; c < 40; ++c) sum += expf(lg[c] - m);
    float lgs = m + logf(sum);
    bool lo1 = (l & 1), hi2 = (l & 2);
    float* op = out + (size_t)node * 40 + l * 10;
    #pragma unroll
    for (int c = 0; c < 10; ++c) {
        float va = lo1 ? lg[10 + c] : lg[c];
        float vb = lo1 ? lg[30 + c] : lg[20 + c];
        float v  = hi2 ? vb : va;
        op[c] = v - lgs;
    }
}

// ---------------- launch ----------------

extern "C" void kernel_launch(void* const* d_in, const int* in_sizes, int n_in,
                              void* d_out, int out_size, void* d_ws, size_t ws_size,
                              hipStream_t stream) {
    const float* x   = (const float*)d_in[0];
    const int*   ei  = (const int*)d_in[1];
    const float* W1a = (const float*)d_in[2];  const float* b1a = (const float*)d_in[3];
    const float* W1b = (const float*)d_in[4];  const float* b1b = (const float*)d_in[5];
    const float* W2a = (const float*)d_in[6];  const float* b2a = (const float*)d_in[7];
    const float* W2b = (const float*)d_in[8];  const float* b2b = (const float*)d_in[9];
    const float* W3a = (const float*)d_in[10]; const float* b3a = (const float*)d_in[11];
    const float* W3b = (const float*)d_in[12]; const float* b3b = (const float*)d_in[13];

    int N = in_sizes[0] / 512;
    int E = in_sizes[1] / 2;
    const int* srcv = ei;
    const int* dstv = ei + E;
    int W = (N + NB - 1) / NB;
    float recipW = 1.0f / (float)W;

    char* ws = (char*)d_ws;
    size_t off = 0;
    auto alloc = [&](size_t bytes) { void* p = ws + off; off = (off + bytes + 255) & ~(size_t)255; return p; };
    int*    offs     = (int*)   alloc((size_t)(N + 1) * 4);
    float*  dinv     = (float*) alloc((size_t)N * 4);
    int*    cursor256= (int*)   alloc(NB * 4);
    int*    csr      = (int*)   alloc((size_t)E * 4);
    ushort* Wt       = (ushort*)alloc(128 * 512 * 2);
    float*  bcat     = (float*) alloc(128 * 4);
    float*  W3s      = (float*) alloc(1280 * 4);
    float*  b3s      = (float*) alloc(40 * 4);
    ushort* HWp      = (ushort*)alloc((size_t)N * 128 * 2);
    ushort* xsp      = (ushort*)alloc((size_t)N * 32 * 2);

    int* epk = (int*)HWp;   // 256*CAP*4 = 16.8MB, aliases HWp (dead until gemm)

    prep_kernel<<<256, 256, 0, stream>>>(W1a, W1b, W2a, W2b, b1a, b1b, b2a, b2b,
                                         W3a, W3b, b3a, b3b, Wt, bcat, W3s, b3s, cursor256);
    bucket_kernel<<<(E + BKE - 1) / BKE, 256, 0, stream>>>(srcv, dstv, cursor256, epk, E, W, recipW);
    sortcsr_kernel<<<NB, 256, 0, stream>>>(epk, cursor256, csr, offs, dinv, N, W, E);
    gemm_mfma<<<(N + GBM - 1) / GBM, 256, 0, stream>>>(x, Wt, dinv, HWp, N);
    agg128<<<((size_t)N * 16 + 255) / 256, 256, 0, stream>>>(HWp, dinv, offs, csr, bcat, xsp, N);
    agg32f<<<((size_t)N * 4 + 255) / 256, 256, 0, stream>>>(xsp, dinv, offs, csr, W3s, b3s,
                                                            (float*)d_out, N);
}

// Round 18
// 303.808 us; speedup vs baseline: 1.0255x; 1.0255x over previous
//
#include <hip/hip_runtime.h>
#include <hip/hip_bf16.h>
#include <math.h>

typedef __attribute__((ext_vector_type(8))) short short8;
typedef __attribute__((ext_vector_type(4))) float f32x4;
typedef __attribute__((ext_vector_type(4))) int i32x4;

__device__ inline ushort f2bf(float f) {
    uint u = __builtin_bit_cast(uint, f);
    u += 0x7fffu + ((u >> 16) & 1u);          // round-to-nearest-even
    return (ushort)(u >> 16);
}
__device__ inline float bf2f(ushort h) {
    return __builtin_bit_cast(float, (uint)h << 16);
}

// ================= CSR build: fixed-capacity bucket counting-sort =================

#define NB   256
#define BKE  2048
#define CAP  16384
#define MAXBE 16384

__device__ inline int bucket_of(int d, int W, float recipW) {
    int g = (int)((float)d * recipW);
    if (g > NB - 1) g = NB - 1;
    if (g < 0) g = 0;
    while (d < g * W) --g;
    while (d >= (g + 1) * W) ++g;
    return g;
}

__global__ __launch_bounds__(256) void bucket_kernel(const int* __restrict__ src, const int* __restrict__ dst,
                                                     int* __restrict__ cursor256, int* __restrict__ epk,
                                                     int E, int W, float recipW) {
    __shared__ int hist[NB];
    __shared__ int base[NB];
    int tid = threadIdx.x;
    int e0 = blockIdx.x * BKE;
    if (e0 >= E) return;
    int e1 = e0 + BKE; if (e1 > E) e1 = E;
    int n4 = (e1 - e0) >> 2;
    hist[tid] = 0;
    __syncthreads();
    const i32x4* d4 = (const i32x4*)(dst + e0);
    const i32x4* s4 = (const i32x4*)(src + e0);
    int myp[8], myg[8], myr[8];
    #pragma unroll
    for (int i = 0; i < 2; ++i) {
        int q = i * 256 + tid;
        if (q < n4) {
            i32x4 dv = d4[q];
            i32x4 sv = s4[q];
            #pragma unroll
            for (int j = 0; j < 4; ++j) {
                int d = dv[j];
                int g = bucket_of(d, W, recipW);
                myp[i * 4 + j] = sv[j] | ((d - g * W) << 17);
                myg[i * 4 + j] = g;
                myr[i * 4 + j] = atomicAdd(&hist[g], 1);
            }
        } else {
            #pragma unroll
            for (int j = 0; j < 4; ++j) myg[i * 4 + j] = -1;
        }
    }
    int tg = -1, tp = 0, tr = 0;
    for (int e = e0 + n4 * 4 + tid; e < e1; e += 256) {
        int d = dst[e];
        int g = bucket_of(d, W, recipW);
        tp = src[e] | ((d - g * W) << 17);
        tg = g;
        tr = atomicAdd(&hist[g], 1);
    }
    __syncthreads();
    base[tid] = atomicAdd(&cursor256[tid], hist[tid]);
    __syncthreads();
    #pragma unroll
    for (int i = 0; i < 8; ++i)
        if (myg[i] >= 0)
            epk[base[myg[i]] + myr[i]] = myp[i];
    if (tg >= 0) epk[base[tg] + tr] = tp;
}

// one block per bucket: inline 256-scan of cursors -> hist -> scan -> offs/dinv -> scatter -> csr
__global__ __launch_bounds__(256) void sortcsr_kernel(const int* __restrict__ epk,
                                                      const int* __restrict__ cursor256,
                                                      int* __restrict__ csr, int* __restrict__ offs,
                                                      float* __restrict__ dinv, int N, int W, int E) {
    __shared__ int lcnt[512];
    __shared__ int lofs[513];
    __shared__ int tmp[256];
    __shared__ int lcsr[MAXBE];
    int b = blockIdx.x;
    int lo = b * W;
    int nloc = N - lo; if (nloc > W) nloc = W; if (nloc < 0) nloc = 0;
    int ebk = b * CAP;
    int tid = threadIdx.x;
    lcnt[2 * tid] = 0; lcnt[2 * tid + 1] = 0;
    tmp[tid] = cursor256[tid] - tid * CAP;    // per-bucket count
    __syncthreads();
    for (int off = 1; off < 256; off <<= 1) {
        int t = (tid >= off) ? tmp[tid - off] : 0;
        __syncthreads();
        tmp[tid] += t;
        __syncthreads();
    }
    int incl = tmp[b];
    int cnt = (b == 0) ? incl : incl - tmp[b - 1];
    int gbase = incl - cnt;
    __syncthreads();
    for (int e = tid; e < cnt; e += 256)
        atomicAdd(&lcnt[epk[ebk + e] >> 17], 1);
    __syncthreads();
    int a0 = lcnt[2 * tid], a1 = lcnt[2 * tid + 1];
    int psum = a0 + a1;
    tmp[tid] = psum;
    __syncthreads();
    for (int off = 1; off < 256; off <<= 1) {
        int t = (tid >= off) ? tmp[tid - off] : 0;
        __syncthreads();
        tmp[tid] += t;
        __syncthreads();
    }
    int excl = tmp[tid] - psum;
    lofs[2 * tid] = excl;
    lofs[2 * tid + 1] = excl + a0;
    lcnt[2 * tid] = excl;
    lcnt[2 * tid + 1] = excl + a0;
    if (tid == 255) lofs[512] = tmp[255];
    __syncthreads();
    for (int t = tid; t < nloc; t += 256) {
        offs[lo + t] = gbase + lofs[t];
        int deg = lofs[t + 1] - lofs[t];
        dinv[lo + t] = rsqrtf((float)(deg + 1));
    }
    if (b == NB - 1 && tid == 0) offs[N] = E;
    for (int e = tid; e < cnt; e += 256) {
        int p = epk[ebk + e];
        int pos = atomicAdd(&lcnt[p >> 17], 1);
        int sv = p & 0x1FFFF;
        if (pos < MAXBE) lcsr[pos] = sv;
        else csr[gbase + pos] = sv;
    }
    __syncthreads();
    int ne = cnt; if (ne > MAXBE) ne = MAXBE;
    for (int e = tid; e < ne; e += 256) csr[gbase + e] = lcsr[e];
}

// ---------------- weight prep (Wt pre-swizzled per 64-k group: chunk c holds c^(row&7)) ------
// + bucket-cursor init (block 0)

__global__ __launch_bounds__(256) void prep_kernel(const float* __restrict__ W1a, const float* __restrict__ W1b,
                                                   const float* __restrict__ W2a, const float* __restrict__ W2b,
                                                   const float* __restrict__ b1a, const float* __restrict__ b1b,
                                                   const float* __restrict__ b2a, const float* __restrict__ b2b,
                                                   const float* __restrict__ W3a, const float* __restrict__ W3b,
                                                   const float* __restrict__ b3a, const float* __restrict__ b3b,
                                                   ushort* __restrict__ Wt, float* __restrict__ bcat,
                                                   float* __restrict__ W3s, float* __restrict__ b3s,
                                                   int* __restrict__ cursor256) {
    int idx = blockIdx.x * 256 + threadIdx.x;
    if (blockIdx.x == 0) cursor256[threadIdx.x] = threadIdx.x * CAP;
    if (idx < 128 * 512) {
        int row = idx >> 9, kk = idx & 511;
        int cstore = (kk >> 3) & 7;
        int clog = cstore ^ (row & 7);
        int klog = (kk & ~63) | (clog << 3) | (kk & 7);
        const float* Wsrc = (row < 32) ? W1a : (row < 64) ? W1b : (row < 96) ? W2a : W2b;
        Wt[idx] = f2bf(Wsrc[klog * 32 + (row & 31)]);
    }
    if (idx < 1280) W3s[idx] = W3a[idx] + W3b[idx];
    if (idx < 128) {
        const float* b = (idx < 32) ? b1a : (idx < 64) ? b1b : (idx < 96) ? b2a : b2b;
        bcat[idx] = b[idx & 31];
    }
    if (idx < 40) b3s[idx] = b3a[idx] + b3b[idx];
}

// ---------------- MFMA GEMM: HWp[N][128] = bf16( (X@Wcat)[r][c] * dinv[r] ) ----------------
// Round-13/16 proven version: async global_load_lds (width 16), BK=64, single-buffered, 32KB LDS.

#define GBM 64

__global__ __launch_bounds__(256) void gemm_mfma(const float* __restrict__ X,
                                                 const ushort* __restrict__ Wt,
                                                 const float* __restrict__ dinv,
                                                 ushort* __restrict__ HWp, int N) {
    __shared__ float  Af[64 * 64];     // pos (row, c) holds logical chunk c^(row&15)
    __shared__ ushort Bl[128 * 64];    // pos (row, c) holds logical chunk c^(row&7)
    const int tid = threadIdx.x;
    const int lane = tid & 63;
    const int wave = tid >> 6;
    const int rQ = lane & 15, g = lane >> 4;
    const int rowBase = blockIdx.x * GBM;

    const float* agsrc[4];
    #pragma unroll
    for (int i = 0; i < 4; ++i) {
        int q = (i * 4 + wave) * 64 + lane;
        int row = q >> 4, c = q & 15;
        int rowg = rowBase + row; if (rowg > N - 1) rowg = N - 1;
        agsrc[i] = X + (size_t)rowg * 512 + ((c ^ (row & 15)) << 2);
    }
    const ushort* bgsrc[4];
    #pragma unroll
    for (int i = 0; i < 4; ++i) {
        int q = (i * 4 + wave) * 64 + lane;
        int row = q >> 3, c = q & 7;
        bgsrc[i] = Wt + (size_t)row * 512 + (c << 3);
    }

    f32x4 acc[4][2] = {};

#define STAGE(s)                                                              \
    {                                                                         \
        _Pragma("unroll")                                                     \
        for (int i = 0; i < 4; ++i)                                           \
            __builtin_amdgcn_global_load_lds(                                 \
                (const uint*)(agsrc[i] + (s) * 64),                           \
                (uint*)&Af[(i * 4 + wave) * 256], 16, 0, 0);                  \
        _Pragma("unroll")                                                     \
        for (int i = 0; i < 4; ++i)                                           \
            __builtin_amdgcn_global_load_lds(                                 \
                (const uint*)(bgsrc[i] + (s) * 64),                           \
                (uint*)&Bl[(i * 4 + wave) * 512], 16, 0, 0);                  \
    }

#define COMPUTE()                                                             \
    {                                                                         \
        short8 bfr[2][2];                                                     \
        _Pragma("unroll")                                                     \
        for (int ct2 = 0; ct2 < 2; ++ct2) {                                   \
            int brow = wave * 32 + ct2 * 16 + rQ;                             \
            _Pragma("unroll")                                                 \
            for (int sub = 0; sub < 2; ++sub)                                 \
                bfr[ct2][sub] = *(const short8*)(&Bl[brow * 64 + (((sub * 4 + g) ^ (brow & 7)) << 3)]); \
        }                                                                     \
        _Pragma("unroll")                                                     \
        for (int rt = 0; rt < 4; ++rt) {                                      \
            int arw = rt * 16 + rQ;                                           \
            _Pragma("unroll")                                                 \
            for (int sub = 0; sub < 2; ++sub) {                               \
                int c0 = (sub * 4 + g) * 2;                                   \
                float4 lo = *(const float4*)(&Af[arw * 64 + ((c0 ^ (arw & 15)) << 2)]);       \
                float4 hi = *(const float4*)(&Af[arw * 64 + (((c0 + 1) ^ (arw & 15)) << 2)]); \
                union { short8 s8; __hip_bfloat162 h[4]; } u;                 \
                u.h[0] = __float22bfloat162_rn({lo.x, lo.y});                 \
                u.h[1] = __float22bfloat162_rn({lo.z, lo.w});                 \
                u.h[2] = __float22bfloat162_rn({hi.x, hi.y});                 \
                u.h[3] = __float22bfloat162_rn({hi.z, hi.w});                 \
                _Pragma("unroll")                                             \
                for (int ct2 = 0; ct2 < 2; ++ct2)                             \
                    acc[rt][ct2] = __builtin_amdgcn_mfma_f32_16x16x32_bf16(   \
                        u.s8, bfr[ct2][sub], acc[rt][ct2], 0, 0, 0);          \
            }                                                                 \
        }                                                                     \
    }

    for (int s = 0; s < 8; ++s) {
        STAGE(s);
        __syncthreads();
        COMPUTE();
        __syncthreads();
    }

    #pragma unroll
    for (int rt = 0; rt < 4; ++rt) {
        #pragma unroll
        for (int j = 0; j < 4; ++j) {
            int r = rowBase + rt * 16 + g * 4 + j;
            if (r < N) {
                float dv = dinv[r];
                #pragma unroll
                for (int ct2 = 0; ct2 < 2; ++ct2) {
                    int c = wave * 32 + ct2 * 16 + rQ;
                    HWp[(size_t)r * 128 + c] = f2bf(acc[rt][ct2][j] * dv);
                }
            }
        }
    }
#undef STAGE
#undef COMPUTE
}

// ---------------- aggregation 128: 16 lanes/node x 16B, unroll 8 ----------------

__global__ __launch_bounds__(256) void agg128(const ushort* __restrict__ HWp, const float* __restrict__ dinv,
                                              const int* __restrict__ offs, const int* __restrict__ csr,
                                              const float* __restrict__ bcat, ushort* __restrict__ xsp, int N) {
    int t = blockIdx.x * 256 + threadIdx.x;
    int node = t >> 4, c = t & 15;
    if (node >= N) return;
    const short8* H = (const short8*)HWp;
    short8 h = H[(size_t)node * 16 + c];
    float a[8];
    #pragma unroll
    for (int i = 0; i < 8; ++i) a[i] = bf2f((ushort)h[i]);
    int j = offs[node];
    int e1 = offs[node + 1];
    int jend = j + ((e1 - j) & ~7);
    for (; j < jend; j += 8) {
        int s[8];
        #pragma unroll
        for (int q = 0; q < 8; ++q) s[q] = csr[j + q];
        short8 v[8];
        #pragma unroll
        for (int q = 0; q < 8; ++q) v[q] = H[(size_t)s[q] * 16 + c];
        #pragma unroll
        for (int q = 0; q < 8; ++q)
            #pragma unroll
            for (int i = 0; i < 8; ++i) a[i] += bf2f((ushort)v[q][i]);
    }
    for (; j < e1; ++j) {
        short8 v = H[(size_t)csr[j] * 16 + c];
        #pragma unroll
        for (int i = 0; i < 8; ++i) a[i] += bf2f((ushort)v[i]);
    }
    float di = dinv[node];
    float4 b0 = *(const float4*)(bcat + c * 8);
    float4 b1 = *(const float4*)(bcat + c * 8 + 4);
    float bb[8] = {b0.x, b0.y, b0.z, b0.w, b1.x, b1.y, b1.z, b1.w};
    float r[8];
    #pragma unroll
    for (int i = 0; i < 8; ++i) r[i] = fmaxf(di * a[i] + bb[i], 0.f);
    #pragma unroll
    for (int i = 0; i < 8; ++i) { r[i] += __shfl_xor(r[i], 4); r[i] += __shfl_xor(r[i], 8); }
    if ((c & 12) == 0) {
        union { short8 s8; ushort us[8]; } o;
        #pragma unroll
        for (int i = 0; i < 8; ++i) o.us[i] = f2bf(r[i] * di);
        *(short8*)(xsp + (size_t)node * 32 + c * 8) = o.s8;
    }
}

// ---------------- aggregation 32 FUSED with final matvec + log_softmax ----------------

__global__ __launch_bounds__(256) void agg32f(const ushort* __restrict__ xsp, const float* __restrict__ dinv,
                                              const int* __restrict__ offs, const int* __restrict__ csr,
                                              const float* __restrict__ W3s, const float* __restrict__ b3s,
                                              float* __restrict__ out, int N) {
    __shared__ float w[32 * 40];
    __shared__ float bsh[40];
    int tid = threadIdx.x;
    for (int i = tid; i < 1280; i += 256) w[i] = W3s[i];
    if (tid < 40) bsh[tid] = b3s[tid];
    __syncthreads();

    int t = blockIdx.x * 256 + tid;
    int node = t >> 2, l = t & 3;
    if (node >= N) return;
    const short8* Xr = (const short8*)xsp;
    short8 h = Xr[(size_t)node * 4 + l];
    float a[8];
    #pragma unroll
    for (int i = 0; i < 8; ++i) a[i] = bf2f((ushort)h[i]);
    int j = offs[node];
    int e1 = offs[node + 1];
    int jend = j + ((e1 - j) & ~7);
    for (; j < jend; j += 8) {
        int s[8];
        #pragma unroll
        for (int q = 0; q < 8; ++q) s[q] = csr[j + q];
        short8 v[8];
        #pragma unroll
        for (int q = 0; q < 8; ++q) v[q] = Xr[(size_t)s[q] * 4 + l];
        #pragma unroll
        for (int q = 0; q < 8; ++q)
            #pragma unroll
            for (int i = 0; i < 8; ++i) a[i] += bf2f((ushort)v[q][i]);
    }
    for (; j < e1; ++j) {
        short8 v = Xr[(size_t)csr[j] * 4 + l];
        #pragma unroll
        for (int i = 0; i < 8; ++i) a[i] += bf2f((ushort)v[i]);
    }
    float di = dinv[node];

    float lg[40];
    #pragma unroll
    for (int c = 0; c < 40; ++c) lg[c] = 0.f;
    #pragma unroll
    for (int k = 0; k < 8; ++k) {
        float av = a[k] * di;
        const float* wr = &w[(l * 8 + k) * 40];
        #pragma unroll
        for (int c = 0; c < 40; ++c) lg[c] += av * wr[c];
    }
    #pragma unroll
    for (int c = 0; c < 40; ++c) {
        lg[c] += __shfl_xor(lg[c], 1);
        lg[c] += __shfl_xor(lg[c], 2);
        lg[c] += bsh[c];
    }
    float m = lg[0];
    #pragma unroll
    for (int c = 1; c < 40; ++c) m = fmaxf(m, lg[c]);
    float sum = 0.f;
    #pragma unroll
    for (int c = 0; c < 40; ++c) sum += expf(lg[c] - m);
    float lgs = m + logf(sum);
    bool lo1 = (l & 1), hi2 = (l & 2);
    float* op = out + (size_t)node * 40 + l * 10;
    #pragma unroll
    for (int c = 0; c < 10; ++c) {
        float va = lo1 ? lg[10 + c] : lg[c];
        float vb = lo1 ? lg[30 + c] : lg[20 + c];
        float v  = hi2 ? vb : va;
        op[c] = v - lgs;
    }
}

// ---------------- launch ----------------

extern "C" void kernel_launch(void* const* d_in, const int* in_sizes, int n_in,
                              void* d_out, int out_size, void* d_ws, size_t ws_size,
                              hipStream_t stream) {
    const float* x   = (const float*)d_in[0];
    const int*   ei  = (const int*)d_in[1];
    const float* W1a = (const float*)d_in[2];  const float* b1a = (const float*)d_in[3];
    const float* W1b = (const float*)d_in[4];  const float* b1b = (const float*)d_in[5];
    const float* W2a = (const float*)d_in[6];  const float* b2a = (const float*)d_in[7];
    const float* W2b = (const float*)d_in[8];  const float* b2b = (const float*)d_in[9];
    const float* W3a = (const float*)d_in[10]; const float* b3a = (const float*)d_in[11];
    const float* W3b = (const float*)d_in[12]; const float* b3b = (const float*)d_in[13];

    int N = in_sizes[0] / 512;
    int E = in_sizes[1] / 2;
    const int* srcv = ei;
    const int* dstv = ei + E;
    int W = (N + NB - 1) / NB;
    float recipW = 1.0f / (float)W;

    char* ws = (char*)d_ws;
    size_t off = 0;
    auto alloc = [&](size_t bytes) { void* p = ws + off; off = (off + bytes + 255) & ~(size_t)255; return p; };
    int*    offs     = (int*)   alloc((size_t)(N + 1) * 4);
    float*  dinv     = (float*) alloc((size_t)N * 4);
    int*    cursor256= (int*)   alloc(NB * 4);
    int*    csr      = (int*)   alloc((size_t)E * 4);
    ushort* Wt       = (ushort*)alloc(128 * 512 * 2);
    float*  bcat     = (float*) alloc(128 * 4);
    float*  W3s      = (float*) alloc(1280 * 4);
    float*  b3s      = (float*) alloc(40 * 4);
    ushort* HWp      = (ushort*)alloc((size_t)N * 128 * 2);
    ushort* xsp      = (ushort*)alloc((size_t)N * 32 * 2);

    int* epk = (int*)HWp;   // 256*CAP*4 = 16.8MB, aliases HWp (dead until gemm)

    prep_kernel<<<256, 256, 0, stream>>>(W1a, W1b, W2a, W2b, b1a, b1b, b2a, b2b,
                                         W3a, W3b, b3a, b3b, Wt, bcat, W3s, b3s, cursor256);
    bucket_kernel<<<(E + BKE - 1) / BKE, 256, 0, stream>>>(srcv, dstv, cursor256, epk, E, W, recipW);
    sortcsr_kernel<<<NB, 256, 0, stream>>>(epk, cursor256, csr, offs, dinv, N, W, E);
    gemm_mfma<<<(N + GBM - 1) / GBM, 256, 0, stream>>>(x, Wt, dinv, HWp, N);
    agg128<<<((size_t)N * 16 + 255) / 256, 256, 0, stream>>>(HWp, dinv, offs, csr, bcat, xsp, N);
    agg32f<<<((size_t)N * 4 + 255) / 256, 256, 0, stream>>>(xsp, dinv, offs, csr, W3s, b3s,
                                                            (float*)d_out, N);
}

// Round 19
// 287.563 us; speedup vs baseline: 1.0834x; 1.0565x over previous
//
#include <hip/hip_runtime.h>
#include <hip/hip_bf16.h>
#include <math.h>

typedef __attribute__((ext_vector_type(8))) short short8;
typedef __attribute__((ext_vector_type(4))) float f32x4;
typedef __attribute__((ext_vector_type(4))) int i32x4;

__device__ inline ushort f2bf(float f) {
    uint u = __builtin_bit_cast(uint, f);
    u += 0x7fffu + ((u >> 16) & 1u);          // round-to-nearest-even
    return (ushort)(u >> 16);
}
__device__ inline float bf2f(ushort h) {
    return __builtin_bit_cast(float, (uint)h << 16);
}

// ================= CSR build: fixed-capacity bucket counting-sort =================
// cursor256 zero-based (memset 0); epk region b = [b*CAP, b*CAP+count_b).

#define NB   256
#define BKE  4096
#define CAP  16384
#define MAXBE 16384

__device__ inline int bucket_of(int d, int W, float recipW) {
    int g = (int)((float)d * recipW);
    if (g > NB - 1) g = NB - 1;
    if (g < 0) g = 0;
    while (d < g * W) --g;
    while (d >= (g + 1) * W) ++g;
    return g;
}

// fused: blocks [0, NBB) bucket 4096 edges each; blocks [NBB, NBB+256) do weight prep.
__global__ __launch_bounds__(256) void prep_bucket_kernel(
        const int* __restrict__ src, const int* __restrict__ dst,
        int* __restrict__ cursor256, int* __restrict__ epk, int E, int W, float recipW, int NBB,
        const float* __restrict__ W1a, const float* __restrict__ W1b,
        const float* __restrict__ W2a, const float* __restrict__ W2b,
        const float* __restrict__ b1a, const float* __restrict__ b1b,
        const float* __restrict__ b2a, const float* __restrict__ b2b,
        const float* __restrict__ W3a, const float* __restrict__ W3b,
        const float* __restrict__ b3a, const float* __restrict__ b3b,
        ushort* __restrict__ Wt, float* __restrict__ bcat,
        float* __restrict__ W3s, float* __restrict__ b3s) {
    int tid = threadIdx.x;
    if (blockIdx.x >= NBB) {
        // ---- prep part ----
        int idx = (blockIdx.x - NBB) * 256 + tid;
        if (idx < 128 * 512) {
            int row = idx >> 9, kk = idx & 511;
            int cstore = (kk >> 3) & 7;
            int clog = cstore ^ (row & 7);
            int klog = (kk & ~63) | (clog << 3) | (kk & 7);
            const float* Wsrc = (row < 32) ? W1a : (row < 64) ? W1b : (row < 96) ? W2a : W2b;
            Wt[idx] = f2bf(Wsrc[klog * 32 + (row & 31)]);
        }
        if (idx < 1280) W3s[idx] = W3a[idx] + W3b[idx];
        if (idx < 128) {
            const float* b = (idx < 32) ? b1a : (idx < 64) ? b1b : (idx < 96) ? b2a : b2b;
            bcat[idx] = b[idx & 31];
        }
        if (idx < 40) b3s[idx] = b3a[idx] + b3b[idx];
        return;
    }
    // ---- bucket part ----
    __shared__ int hist[NB];
    __shared__ int base[NB];
    int e0 = blockIdx.x * BKE;
    if (e0 >= E) return;
    int e1 = e0 + BKE; if (e1 > E) e1 = E;
    int n4 = (e1 - e0) >> 2;
    hist[tid] = 0;
    __syncthreads();
    const i32x4* d4 = (const i32x4*)(dst + e0);
    const i32x4* s4 = (const i32x4*)(src + e0);
    int myp[16], myg[16], myr[16];
    #pragma unroll
    for (int i = 0; i < 4; ++i) {
        int q = i * 256 + tid;
        if (q < n4) {
            i32x4 dv = d4[q];
            i32x4 sv = s4[q];
            #pragma unroll
            for (int j = 0; j < 4; ++j) {
                int d = dv[j];
                int g = bucket_of(d, W, recipW);
                myp[i * 4 + j] = sv[j] | ((d - g * W) << 17);
                myg[i * 4 + j] = g;
                myr[i * 4 + j] = atomicAdd(&hist[g], 1);
            }
        } else {
            #pragma unroll
            for (int j = 0; j < 4; ++j) myg[i * 4 + j] = -1;
        }
    }
    int tg = -1, tp = 0, tr = 0;
    for (int e = e0 + n4 * 4 + tid; e < e1; e += 256) {
        int d = dst[e];
        int g = bucket_of(d, W, recipW);
        tp = src[e] | ((d - g * W) << 17);
        tg = g;
        tr = atomicAdd(&hist[g], 1);
    }
    __syncthreads();
    base[tid] = tid * CAP + atomicAdd(&cursor256[tid], hist[tid]);
    __syncthreads();
    #pragma unroll
    for (int i = 0; i < 16; ++i)
        if (myg[i] >= 0)
            epk[base[myg[i]] + myr[i]] = myp[i];
    if (tg >= 0) epk[base[tg] + tr] = tp;
}

// one block per bucket: inline 256-scan of counts -> hist -> scan -> offs/dinv -> scatter -> csr
__global__ __launch_bounds__(256) void sortcsr_kernel(const int* __restrict__ epk,
                                                      const int* __restrict__ cursor256,
                                                      int* __restrict__ csr, int* __restrict__ offs,
                                                      float* __restrict__ dinv, int N, int W, int E) {
    __shared__ int lcnt[512];
    __shared__ int lofs[513];
    __shared__ int tmp[256];
    __shared__ int lcsr[MAXBE];
    int b = blockIdx.x;
    int lo = b * W;
    int nloc = N - lo; if (nloc > W) nloc = W; if (nloc < 0) nloc = 0;
    int ebk = b * CAP;
    int tid = threadIdx.x;
    lcnt[2 * tid] = 0; lcnt[2 * tid + 1] = 0;
    tmp[tid] = cursor256[tid];               // per-bucket count (zero-based cursors)
    __syncthreads();
    for (int off = 1; off < 256; off <<= 1) {
        int t = (tid >= off) ? tmp[tid - off] : 0;
        __syncthreads();
        tmp[tid] += t;
        __syncthreads();
    }
    int incl = tmp[b];
    int cnt = (b == 0) ? incl : incl - tmp[b - 1];
    int gbase = incl - cnt;
    __syncthreads();
    for (int e = tid; e < cnt; e += 256)
        atomicAdd(&lcnt[epk[ebk + e] >> 17], 1);
    __syncthreads();
    int a0 = lcnt[2 * tid], a1 = lcnt[2 * tid + 1];
    int psum = a0 + a1;
    tmp[tid] = psum;
    __syncthreads();
    for (int off = 1; off < 256; off <<= 1) {
        int t = (tid >= off) ? tmp[tid - off] : 0;
        __syncthreads();
        tmp[tid] += t;
        __syncthreads();
    }
    int excl = tmp[tid] - psum;
    lofs[2 * tid] = excl;
    lofs[2 * tid + 1] = excl + a0;
    lcnt[2 * tid] = excl;
    lcnt[2 * tid + 1] = excl + a0;
    if (tid == 255) lofs[512] = tmp[255];
    __syncthreads();
    for (int t = tid; t < nloc; t += 256) {
        offs[lo + t] = gbase + lofs[t];
        int deg = lofs[t + 1] - lofs[t];
        dinv[lo + t] = rsqrtf((float)(deg + 1));
    }
    if (b == NB - 1 && tid == 0) offs[N] = E;
    for (int e = tid; e < cnt; e += 256) {
        int p = epk[ebk + e];
        int pos = atomicAdd(&lcnt[p >> 17], 1);
        int sv = p & 0x1FFFF;
        if (pos < MAXBE) lcsr[pos] = sv;
        else csr[gbase + pos] = sv;
    }
    __syncthreads();
    int ne = cnt; if (ne > MAXBE) ne = MAXBE;
    for (int e = tid; e < ne; e += 256) csr[gbase + e] = lcsr[e];
}

// ---------------- MFMA GEMM: HWp[N][128] = bf16( (X@Wcat)[r][c] * dinv[r] ) ----------------
// Round-13/16 proven version: async global_load_lds (width 16), BK=64, single-buffered, 32KB LDS.

#define GBM 64

__global__ __launch_bounds__(256) void gemm_mfma(const float* __restrict__ X,
                                                 const ushort* __restrict__ Wt,
                                                 const float* __restrict__ dinv,
                                                 ushort* __restrict__ HWp, int N) {
    __shared__ float  Af[64 * 64];     // pos (row, c) holds logical chunk c^(row&15)
    __shared__ ushort Bl[128 * 64];    // pos (row, c) holds logical chunk c^(row&7)
    const int tid = threadIdx.x;
    const int lane = tid & 63;
    const int wave = tid >> 6;
    const int rQ = lane & 15, g = lane >> 4;
    const int rowBase = blockIdx.x * GBM;

    const float* agsrc[4];
    #pragma unroll
    for (int i = 0; i < 4; ++i) {
        int q = (i * 4 + wave) * 64 + lane;
        int row = q >> 4, c = q & 15;
        int rowg = rowBase + row; if (rowg > N - 1) rowg = N - 1;
        agsrc[i] = X + (size_t)rowg * 512 + ((c ^ (row & 15)) << 2);
    }
    const ushort* bgsrc[4];
    #pragma unroll
    for (int i = 0; i < 4; ++i) {
        int q = (i * 4 + wave) * 64 + lane;
        int row = q >> 3, c = q & 7;
        bgsrc[i] = Wt + (size_t)row * 512 + (c << 3);
    }

    f32x4 acc[4][2] = {};

#define STAGE(s)                                                              \
    {                                                                         \
        _Pragma("unroll")                                                     \
        for (int i = 0; i < 4; ++i)                                           \
            __builtin_amdgcn_global_load_lds(                                 \
                (const uint*)(agsrc[i] + (s) * 64),                           \
                (uint*)&Af[(i * 4 + wave) * 256], 16, 0, 0);                  \
        _Pragma("unroll")                                                     \
        for (int i = 0; i < 4; ++i)                                           \
            __builtin_amdgcn_global_load_lds(                                 \
                (const uint*)(bgsrc[i] + (s) * 64),                           \
                (uint*)&Bl[(i * 4 + wave) * 512], 16, 0, 0);                  \
    }

#define COMPUTE()                                                             \
    {                                                                         \
        short8 bfr[2][2];                                                     \
        _Pragma("unroll")                                                     \
        for (int ct2 = 0; ct2 < 2; ++ct2) {                                   \
            int brow = wave * 32 + ct2 * 16 + rQ;                             \
            _Pragma("unroll")                                                 \
            for (int sub = 0; sub < 2; ++sub)                                 \
                bfr[ct2][sub] = *(const short8*)(&Bl[brow * 64 + (((sub * 4 + g) ^ (brow & 7)) << 3)]); \
        }                                                                     \
        _Pragma("unroll")                                                     \
        for (int rt = 0; rt < 4; ++rt) {                                      \
            int arw = rt * 16 + rQ;                                           \
            _Pragma("unroll")                                                 \
            for (int sub = 0; sub < 2; ++sub) {                               \
                int c0 = (sub * 4 + g) * 2;                                   \
                float4 lo = *(const float4*)(&Af[arw * 64 + ((c0 ^ (arw & 15)) << 2)]);       \
                float4 hi = *(const float4*)(&Af[arw * 64 + (((c0 + 1) ^ (arw & 15)) << 2)]); \
                union { short8 s8; __hip_bfloat162 h[4]; } u;                 \
                u.h[0] = __float22bfloat162_rn({lo.x, lo.y});                 \
                u.h[1] = __float22bfloat162_rn({lo.z, lo.w});                 \
                u.h[2] = __float22bfloat162_rn({hi.x, hi.y});                 \
                u.h[3] = __float22bfloat162_rn({hi.z, hi.w});                 \
                _Pragma("unroll")                                             \
                for (int ct2 = 0; ct2 < 2; ++ct2)                             \
                    acc[rt][ct2] = __builtin_amdgcn_mfma_f32_16x16x32_bf16(   \
                        u.s8, bfr[ct2][sub], acc[rt][ct2], 0, 0, 0);          \
            }                                                                 \
        }                                                                     \
    }

    for (int s = 0; s < 8; ++s) {
        STAGE(s);
        __syncthreads();
        COMPUTE();
        __syncthreads();
    }

    #pragma unroll
    for (int rt = 0; rt < 4; ++rt) {
        #pragma unroll
        for (int j = 0; j < 4; ++j) {
            int r = rowBase + rt * 16 + g * 4 + j;
            if (r < N) {
                float dv = dinv[r];
                #pragma unroll
                for (int ct2 = 0; ct2 < 2; ++ct2) {
                    int c = wave * 32 + ct2 * 16 + rQ;
                    HWp[(size_t)r * 128 + c] = f2bf(acc[rt][ct2][j] * dv);
                }
            }
        }
    }
#undef STAGE
#undef COMPUTE
}

// ---------------- aggregation 128: 16 lanes/node x 16B, unroll 8 ----------------

__global__ __launch_bounds__(256) void agg128(const ushort* __restrict__ HWp, const float* __restrict__ dinv,
                                              const int* __restrict__ offs, const int* __restrict__ csr,
                                              const float* __restrict__ bcat, ushort* __restrict__ xsp, int N) {
    int t = blockIdx.x * 256 + threadIdx.x;
    int node = t >> 4, c = t & 15;
    if (node >= N) return;
    const short8* H = (const short8*)HWp;
    short8 h = H[(size_t)node * 16 + c];
    float a[8];
    #pragma unroll
    for (int i = 0; i < 8; ++i) a[i] = bf2f((ushort)h[i]);
    int j = offs[node];
    int e1 = offs[node + 1];
    int jend = j + ((e1 - j) & ~7);
    for (; j < jend; j += 8) {
        int s[8];
        #pragma unroll
        for (int q = 0; q < 8; ++q) s[q] = csr[j + q];
        short8 v[8];
        #pragma unroll
        for (int q = 0; q < 8; ++q) v[q] = H[(size_t)s[q] * 16 + c];
        #pragma unroll
        for (int q = 0; q < 8; ++q)
            #pragma unroll
            for (int i = 0; i < 8; ++i) a[i] += bf2f((ushort)v[q][i]);
    }
    for (; j < e1; ++j) {
        short8 v = H[(size_t)csr[j] * 16 + c];
        #pragma unroll
        for (int i = 0; i < 8; ++i) a[i] += bf2f((ushort)v[i]);
    }
    float di = dinv[node];
    float4 b0 = *(const float4*)(bcat + c * 8);
    float4 b1 = *(const float4*)(bcat + c * 8 + 4);
    float bb[8] = {b0.x, b0.y, b0.z, b0.w, b1.x, b1.y, b1.z, b1.w};
    float r[8];
    #pragma unroll
    for (int i = 0; i < 8; ++i) r[i] = fmaxf(di * a[i] + bb[i], 0.f);
    #pragma unroll
    for (int i = 0; i < 8; ++i) { r[i] += __shfl_xor(r[i], 4); r[i] += __shfl_xor(r[i], 8); }
    if ((c & 12) == 0) {
        union { short8 s8; ushort us[8]; } o;
        #pragma unroll
        for (int i = 0; i < 8; ++i) o.us[i] = f2bf(r[i] * di);
        *(short8*)(xsp + (size_t)node * 32 + c * 8) = o.s8;
    }
}

// ---------------- aggregation 32 FUSED with final matvec + log_softmax ----------------

__global__ __launch_bounds__(256) void agg32f(const ushort* __restrict__ xsp, const float* __restrict__ dinv,
                                              const int* __restrict__ offs, const int* __restrict__ csr,
                                              const float* __restrict__ W3s, const float* __restrict__ b3s,
                                              float* __restrict__ out, int N) {
    __shared__ float w[32 * 40];
    __shared__ float bsh[40];
    int tid = threadIdx.x;
    for (int i = tid; i < 1280; i += 256) w[i] = W3s[i];
    if (tid < 40) bsh[tid] = b3s[tid];
    __syncthreads();

    int t = blockIdx.x * 256 + tid;
    int node = t >> 2, l = t & 3;
    if (node >= N) return;
    const short8* Xr = (const short8*)xsp;
    short8 h = Xr[(size_t)node * 4 + l];
    float a[8];
    #pragma unroll
    for (int i = 0; i < 8; ++i) a[i] = bf2f((ushort)h[i]);
    int j = offs[node];
    int e1 = offs[node + 1];
    int jend = j + ((e1 - j) & ~7);
    for (; j < jend; j += 8) {
        int s[8];
        #pragma unroll
        for (int q = 0; q < 8; ++q) s[q] = csr[j + q];
        short8 v[8];
        #pragma unroll
        for (int q = 0; q < 8; ++q) v[q] = Xr[(size_t)s[q] * 4 + l];
        #pragma unroll
        for (int q = 0; q < 8; ++q)
            #pragma unroll
            for (int i = 0; i < 8; ++i) a[i] += bf2f((ushort)v[q][i]);
    }
    for (; j < e1; ++j) {
        short8 v = Xr[(size_t)csr[j] * 4 + l];
        #pragma unroll
        for (int i = 0; i < 8; ++i) a[i] += bf2f((ushort)v[i]);
    }
    float di = dinv[node];

    float lg[40];
    #pragma unroll
    for (int c = 0; c < 40; ++c) lg[c] = 0.f;
    #pragma unroll
    for (int k = 0; k < 8; ++k) {
        float av = a[k] * di;
        const float* wr = &w[(l * 8 + k) * 40];
        #pragma unroll
        for (int c = 0; c < 40; ++c) lg[c] += av * wr[c];
    }
    #pragma unroll
    for (int c = 0; c < 40; ++c) {
        lg[c] += __shfl_xor(lg[c], 1);
        lg[c] += __shfl_xor(lg[c], 2);
        lg[c] += bsh[c];
    }
    float m = lg[0];
    #pragma unroll
    for (int c = 1; c < 40; ++c) m = fmaxf(m, lg[c]);
    float sum = 0.f;
    #pragma unroll
    for (int c = 0; c < 40; ++c) sum += expf(lg[c] - m);
    float lgs = m + logf(sum);
    bool lo1 = (l & 1), hi2 = (l & 2);
    float* op = out + (size_t)node * 40 + l * 10;
    #pragma unroll
    for (int c = 0; c < 10; ++c) {
        float va = lo1 ? lg[10 + c] : lg[c];
        float vb = lo1 ? lg[30 + c] : lg[20 + c];
        float v  = hi2 ? vb : va;
        op[c] = v - lgs;
    }
}

// ---------------- launch ----------------

extern "C" void kernel_launch(void* const* d_in, const int* in_sizes, int n_in,
                              void* d_out, int out_size, void* d_ws, size_t ws_size,
                              hipStream_t stream) {
    const float* x   = (const float*)d_in[0];
    const int*   ei  = (const int*)d_in[1];
    const float* W1a = (const float*)d_in[2];  const float* b1a = (const float*)d_in[3];
    const float* W1b = (const float*)d_in[4];  const float* b1b = (const float*)d_in[5];
    const float* W2a = (const float*)d_in[6];  const float* b2a = (const float*)d_in[7];
    const float* W2b = (const float*)d_in[8];  const float* b2b = (const float*)d_in[9];
    const float* W3a = (const float*)d_in[10]; const float* b3a = (const float*)d_in[11];
    const float* W3b = (const float*)d_in[12]; const float* b3b = (const float*)d_in[13];

    int N = in_sizes[0] / 512;
    int E = in_sizes[1] / 2;
    const int* srcv = ei;
    const int* dstv = ei + E;
    int W = (N + NB - 1) / NB;
    float recipW = 1.0f / (float)W;
    int NBB = (E + BKE - 1) / BKE;

    char* ws = (char*)d_ws;
    size_t off = 0;
    auto alloc = [&](size_t bytes) { void* p = ws + off; off = (off + bytes + 255) & ~(size_t)255; return p; };
    int*    offs     = (int*)   alloc((size_t)(N + 1) * 4);
    float*  dinv     = (float*) alloc((size_t)N * 4);
    int*    cursor256= (int*)   alloc(NB * 4);
    int*    csr      = (int*)   alloc((size_t)E * 4);
    ushort* Wt       = (ushort*)alloc(128 * 512 * 2);
    float*  bcat     = (float*) alloc(128 * 4);
    float*  W3s      = (float*) alloc(1280 * 4);
    float*  b3s      = (float*) alloc(40 * 4);
    ushort* HWp      = (ushort*)alloc((size_t)N * 128 * 2);
    ushort* xsp      = (ushort*)alloc((size_t)N * 32 * 2);

    int* epk = (int*)HWp;   // 256*CAP*4 = 16.8MB, aliases HWp (dead until gemm)

    hipMemsetAsync(cursor256, 0, NB * 4, stream);
    prep_bucket_kernel<<<NBB + 256, 256, 0, stream>>>(
        srcv, dstv, cursor256, epk, E, W, recipW, NBB,
        W1a, W1b, W2a, W2b, b1a, b1b, b2a, b2b, W3a, W3b, b3a, b3b,
        Wt, bcat, W3s, b3s);
    sortcsr_kernel<<<NB, 256, 0, stream>>>(epk, cursor256, csr, offs, dinv, N, W, E);
    gemm_mfma<<<(N + GBM - 1) / GBM, 256, 0, stream>>>(x, Wt, dinv, HWp, N);
    agg128<<<((size_t)N * 16 + 255) / 256, 256, 0, stream>>>(HWp, dinv, offs, csr, bcat, xsp, N);
    agg32f<<<((size_t)N * 4 + 255) / 256, 256, 0, stream>>>(xsp, dinv, offs, csr, W3s, b3s,
                                                            (float*)d_out, N);
}